// Round 13
// baseline (313.677 us; speedup 1.0000x reference)
//
#include <hip/hip_runtime.h>
#include <hip/hip_bf16.h>

// B=16, D=256, H=64, W=64, S=4096, P=8, tokens T=64, E=D*64=16384
// Inputs/outputs FLOAT32 (per reference). Intermediates bf16.
#define BB 16
#define SS 4096

typedef __attribute__((ext_vector_type(8))) short short8;
typedef __attribute__((ext_vector_type(4))) float float4v;

// ---------------------------------------------------------------------------
// K0: fused weight prep. blocks [0,288): conv W -> B-frag blob.
// blocks [288,384): Wq/Wk/Wv -> A-frag blob.
// ---------------------------------------------------------------------------
__global__ __launch_bounds__(256) void wprep_all(
    const float* __restrict__ wo, const float* __restrict__ wq,
    const float* __restrict__ wk, const float* __restrict__ wv,
    __hip_bfloat16* __restrict__ blob, __hip_bfloat16* __restrict__ blob_a) {
  const int bid = blockIdx.x;
  const int tid = threadIdx.x;
  if (bid < 288) {
    int chunk = bid * 256 + tid;  // 73728 = 9*8*16*64 exact
    int l = chunk & 63;
    int ob = (chunk >> 6) & 15;
    int cb = (chunk >> 10) & 7;
    int tap = chunk >> 13;
    int o = ob * 16 + (l & 15);
    int c0 = cb * 32 + (l >> 4) * 8;
    union { uint4 u; __hip_bfloat16 h[8]; } t;
#pragma unroll
    for (int j = 0; j < 8; ++j)
      t.h[j] = __float2bfloat16(wo[((size_t)(o * 256 + c0 + j)) * 9 + tap]);
    *reinterpret_cast<uint4*>(blob + (size_t)chunk * 8) = t.u;
  } else {
    int chunk = (bid - 288) * 256 + tid;  // 24576 = 3*8*16*64 exact
    int lane = chunk & 63;
    int ob = (chunk >> 6) & 15;
    int cb = (chunk >> 10) & 7;
    int which = chunk >> 13;
    const float* W = (which == 0) ? wq : (which == 1) ? wk : wv;
    int o = ob * 16 + (lane & 15);
    int c0 = cb * 32 + (lane >> 4) * 8;
    const float* p = W + o * 256 + c0;
    union { uint4 u; __hip_bfloat16 h[8]; } t;
#pragma unroll
    for (int j = 0; j < 8; ++j) t.h[j] = __float2bfloat16(p[j]);
    *reinterpret_cast<uint4*>(blob_a + (size_t)chunk * 8) = t.u;
  }
}

// ---------------------------------------------------------------------------
// K1: MFMA QKV GEMM (3-pass: blockIdx.z = which). v8 main loop (unswapped,
// dbuf LDS, 1 barrier/cb). R10: q/k epilogue LDS transpose (8x128B segments
// per store instr). R12: same mechanism for the v pass (old uint2 NHWC
// stores were 64x8B isolated segments/instr). Both verified.
// ---------------------------------------------------------------------------
__global__ __launch_bounds__(256, 4) void qkv_mfma(
    const float* __restrict__ x, const __hip_bfloat16* __restrict__ blob,
    const float* __restrict__ bq, const float* __restrict__ bk,
    const float* __restrict__ bv,
    __hip_bfloat16* __restrict__ qb, __hip_bfloat16* __restrict__ kb,
    __hip_bfloat16* __restrict__ vb) {
  __shared__ short ls[9216];  // staging: 2 x 2560; epilogue: per-wave regions
  const int which = blockIdx.z;
  const int b = blockIdx.y;
  const int s0 = blockIdx.x * 64;
  const float* bias = (which == 0) ? bq : (which == 1) ? bk : bv;
  __hip_bfloat16* outb = (which == 0) ? qb : kb;  // v handled separately
  const int tid = threadIdx.x;
  const int wave = tid >> 6, lane = tid & 63;
  const int q = lane >> 4, m = lane & 15;
  const int sl = tid & 63;
  const int cg = tid >> 6;
  float4v acc[4][4] = {};  // [of][sf]; row = o-sub (q*4+r), col = s-sub (m)

  const float* xbase = x + ((size_t)(b * 256 + cg * 8)) * SS + s0 + sl;
  float xr[8];
#pragma unroll
  for (int i = 0; i < 8; ++i) xr[i] = xbase[(size_t)i * SS];
  {
    union { uint4 u; __hip_bfloat16 h[8]; } t;
#pragma unroll
    for (int i = 0; i < 8; ++i) t.h[i] = __float2bfloat16(xr[i]);
    *reinterpret_cast<uint4*>(&ls[sl * 40 + cg * 8]) = t.u;
  }
  __syncthreads();

  for (int cb = 0; cb < 8; ++cb) {
    const short* cur = &ls[(cb & 1) * 2560];
    short* nxt = &ls[((cb + 1) & 1) * 2560];
    if (cb < 7) {
#pragma unroll
      for (int i = 0; i < 8; ++i)
        xr[i] = xbase[(size_t)(cb + 1) * 32 * SS + (size_t)i * SS];
    }
    short8 af[4];
#pragma unroll
    for (int of = 0; of < 4; ++of)
      af[of] = *reinterpret_cast<const short8*>(
          blob +
          ((size_t)(((which * 8 + cb) * 16 + wave * 4 + of) * 64 + lane)) * 8);
    short8 xf[4];
#pragma unroll
    for (int sf = 0; sf < 4; ++sf)
      xf[sf] =
          *reinterpret_cast<const short8*>(&cur[(sf * 16 + m) * 40 + q * 8]);
#pragma unroll
    for (int of = 0; of < 4; ++of)
#pragma unroll
      for (int sf = 0; sf < 4; ++sf)
        acc[of][sf] = __builtin_amdgcn_mfma_f32_16x16x32_bf16(
            af[of], xf[sf], acc[of][sf], 0, 0, 0);
    if (cb < 7) {
      union { uint4 u; __hip_bfloat16 h[8]; } t;
#pragma unroll
      for (int i = 0; i < 8; ++i) t.h[i] = __float2bfloat16(xr[i]);
      *reinterpret_cast<uint4*>(&nxt[sl * 40 + cg * 8]) = t.u;
    }
    __syncthreads();
  }
  if (which == 2) {
    // v NHWC via per-wave epilogue LDS transpose. Wave owns o-range
    // [wave*64, wave*64+64) x all 64 w of pixel row h. Two 32-w halves
    // through a private [32 w][72] region (stride 144B keeps b128 align).
    const int h = s0 >> 6;
    __hip_bfloat16* tw = reinterpret_cast<__hip_bfloat16*>(ls) + wave * 2304;
#pragma unroll
    for (int wh = 0; wh < 2; ++wh) {
      // write phase: lane (q,m) drops 32 values (2 sf x 4 of x 4 r)
#pragma unroll
      for (int sf2 = 0; sf2 < 2; ++sf2) {
        int sf = wh * 2 + sf2;
#pragma unroll
        for (int of = 0; of < 4; ++of)
#pragma unroll
          for (int r = 0; r < 4; ++r)
            tw[(sf2 * 16 + m) * 72 + of * 16 + q * 4 + r] = __float2bfloat16(
                acc[of][sf][r] + bias[wave * 64 + of * 16 + q * 4 + r]);
      }
      // read+store: instr i covers 8 w-pixels x 128B contiguous each
#pragma unroll
      for (int i = 0; i < 4; ++i) {
        int w_local = i * 8 + (lane >> 3);
        int oc = lane & 7;
        uint4 vv =
            *reinterpret_cast<const uint4*>(&tw[w_local * 72 + oc * 8]);
        int w = wh * 32 + w_local;
        *reinterpret_cast<uint4*>(vb +
                                  ((size_t)((b * 64 + h) * 64 + w)) * 256 +
                                  wave * 64 + oc * 8) = vv;
      }
    }
  } else {
    // q/k: per-wave LDS transpose (16x72-short private region; 72-stride
    // keeps rows 144B = 16B-aligned for b128 reads). Last __syncthreads()
    // above guarantees all waves are done with the staging buffers.
    __hip_bfloat16* tw =
        reinterpret_cast<__hip_bfloat16*>(ls) + wave * (16 * 72);
#pragma unroll
    for (int of = 0; of < 4; ++of) {
      // write phase: lane (q,m) drops its 16 values at [q*4+r][sf*16+m]
#pragma unroll
      for (int sf = 0; sf < 4; ++sf)
#pragma unroll
        for (int r = 0; r < 4; ++r)
          tw[(q * 4 + r) * 72 + sf * 16 + m] = __float2bfloat16(
              acc[of][sf][r] + bias[wave * 64 + of * 16 + q * 4 + r]);
      // read+store: 8 o-rows x 128B contiguous per instruction
#pragma unroll
      for (int it = 0; it < 2; ++it) {
        int o_local = (lane >> 3) + it * 8;
        int s_oct = lane & 7;
        uint4 vv =
            *reinterpret_cast<const uint4*>(&tw[o_local * 72 + s_oct * 8]);
        int o = wave * 64 + of * 16 + o_local;
        *reinterpret_cast<uint4*>(outb + (size_t)(b * 256 + o) * SS + s0 +
                                  s_oct * 8) = vv;
      }
    }
  }
}

// ---------------------------------------------------------------------------
// K2: MFMA scores. Writes per-d-slice PARTIALS (no atomics, no memset);
// softmax sums the 64 slices. part[slice][b][t][t'] f32.
// v13: grid 32->64 in x (4 d-rows per block): scores is a serial load->MFMA
// chain; at 32 blocks/b it ran ~2 blocks/CU. 64 blocks/b = 4 blocks/CU
// doubles the latency-hiding TLP (same direction as the verified R5->R6
// 16->32 split).
// ---------------------------------------------------------------------------
__global__ __launch_bounds__(256) void scores_mfma(
    const __hip_bfloat16* __restrict__ qb, const __hip_bfloat16* __restrict__ kb,
    float* __restrict__ part) {
  const int b = blockIdx.y;
  const int d0 = blockIdx.x * 4;
  const int tid = threadIdx.x;
  const int wave = tid >> 6, lane = tid & 63;
  const int q = lane >> 4, m = lane & 15;
  const int t = wave * 16 + m;
  const int arow = (t >> 3) * 8;
  const int acol = (t & 7) * 8;
  float4v acc[4] = {};

  for (int dd = 0; dd < 4; ++dd) {
    const int d = d0 + dd;
    const __hip_bfloat16* qp = qb + ((size_t)(b * 256 + d)) * SS;
    const __hip_bfloat16* kp = kb + ((size_t)(b * 256 + d)) * SS;
#pragma unroll
    for (int khalf = 0; khalf < 2; ++khalf) {
      const int oh = khalf * 4 + q;
      short8 af = *reinterpret_cast<const short8*>(
          qp + (arow + oh) * 64 + acol);
      short8 bf[4];
#pragma unroll
      for (int nt = 0; nt < 4; ++nt) {
        int tp = nt * 16 + m;
        bf[nt] = *reinterpret_cast<const short8*>(
            kp + ((tp >> 3) * 8 + oh) * 64 + (tp & 7) * 8);
      }
#pragma unroll
      for (int nt = 0; nt < 4; ++nt)
        acc[nt] = __builtin_amdgcn_mfma_f32_16x16x32_bf16(af, bf[nt], acc[nt],
                                                          0, 0, 0);
    }
  }
  float* pp = part + ((size_t)(blockIdx.x * BB + b)) * 4096;
#pragma unroll
  for (int nt = 0; nt < 4; ++nt)
#pragma unroll
    for (int r = 0; r < 4; ++r)
      pp[(wave * 16 + q * 4 + r) * 64 + nt * 16 + m] = acc[nt][r];
}

// ---------------------------------------------------------------------------
// K3: softmax over t' with scale 1/128; sums 64 d-slice partials first.
// ---------------------------------------------------------------------------
__global__ __launch_bounds__(64) void softmax_kernel(
    const float* __restrict__ part, __hip_bfloat16* __restrict__ attnb) {
  const int t = blockIdx.x;
  const int b = blockIdx.y;
  const int lane = threadIdx.x;
  float v = 0.f;
#pragma unroll
  for (int sl = 0; sl < 64; ++sl)
    v += part[((size_t)(sl * BB + b)) * 4096 + t * 64 + lane];
  v *= 0.0078125f;  // 1/sqrt(16384)
  float m = v;
#pragma unroll
  for (int off = 32; off >= 1; off >>= 1) m = fmaxf(m, __shfl_xor(m, off));
  float e = __expf(v - m);
  float s = e;
#pragma unroll
  for (int off = 32; off >= 1; off >>= 1) s += __shfl_xor(s, off);
  attnb[(b * 64 + t) * 64 + lane] = __float2bfloat16(e / s);
}

// ---------------------------------------------------------------------------
// K4: MFMA apply. z[t][d] = sum_t' attn[t][t'] V[t'][d]; z NHWC bf16.
// R11 form: epilogue LDS transpose for the z store.
// ---------------------------------------------------------------------------
__global__ __launch_bounds__(256) void apply_mfma(
    const __hip_bfloat16* __restrict__ attnb, const __hip_bfloat16* __restrict__ vb,
    __hip_bfloat16* __restrict__ zb) {
  __shared__ short sbuf[4 * 64 * 72];  // 36864B; phase1: Vs[64][268]
  short (*Vs)[268] = reinterpret_cast<short(*)[268]>(sbuf);
  const int off = blockIdx.x;
  const int b = blockIdx.y;
  const int oh = off >> 3, ow = off & 7;
  const int tid = threadIdx.x;
#pragma unroll
  for (int i = 0; i < 8; ++i) {
    int chunk = i * 256 + tid;
    int tp = chunk >> 5;
    int cg = chunk & 31;
    int hh = (tp >> 3) * 8 + oh;
    int wwp = (tp & 7) * 8 + ow;
    uint4 val = *reinterpret_cast<const uint4*>(
        vb + ((size_t)((b * 64 + hh) * 64 + wwp)) * 256 + cg * 8);
    *reinterpret_cast<uint4*>(&Vs[tp][cg * 8]) = val;
  }
  __syncthreads();
  const int wave = tid >> 6, lane = tid & 63;
  const int q = lane >> 4, m = lane & 15;
  float4v acc[4][4] = {};
#pragma unroll
  for (int ks = 0; ks < 2; ++ks) {
    short8 af[4];
#pragma unroll
    for (int mt = 0; mt < 4; ++mt)
      af[mt] = *reinterpret_cast<const short8*>(
          attnb + (b * 64 + mt * 16 + m) * 64 + ks * 32 + q * 8);
    short8 bf[4];
#pragma unroll
    for (int nt = 0; nt < 4; ++nt) {
      int d = wave * 64 + nt * 16 + m;
      union { short8 v; short s[8]; } t;
#pragma unroll
      for (int j = 0; j < 8; ++j) t.s[j] = Vs[ks * 32 + q * 8 + j][d];
      bf[nt] = t.v;
    }
#pragma unroll
    for (int mt = 0; mt < 4; ++mt)
#pragma unroll
      for (int nt = 0; nt < 4; ++nt)
        acc[mt][nt] = __builtin_amdgcn_mfma_f32_16x16x32_bf16(
            af[mt], bf[nt], acc[mt][nt], 0, 0, 0);
  }
  // --- epilogue transpose: all waves must be done reading Vs ---
  __syncthreads();
  short* tw = &sbuf[wave * 64 * 72];
#pragma unroll
  for (int mt = 0; mt < 4; ++mt)
#pragma unroll
    for (int r = 0; r < 4; ++r) {
      int t = mt * 16 + q * 4 + r;
#pragma unroll
      for (int nt = 0; nt < 4; ++nt) {
        __hip_bfloat16 hv = __float2bfloat16(acc[mt][nt][r]);
        tw[t * 72 + nt * 16 + m] = *reinterpret_cast<short*>(&hv);
      }
    }
#pragma unroll
  for (int i = 0; i < 8; ++i) {
    int t = i * 8 + (lane >> 3);
    int dg = lane & 7;
    uint4 vv = *reinterpret_cast<const uint4*>(&tw[t * 72 + dg * 8]);
    int h = (t >> 3) * 8 + oh;
    int w = (t & 7) * 8 + ow;
    *reinterpret_cast<uint4*>(
        zb + ((size_t)((b * 64 + h) * 64 + w)) * 256 + wave * 64 + dg * 8) =
        vv;
  }
}

// ---------------------------------------------------------------------------
// K5: MFMA implicit-GEMM 3x3 conv + bias + BN + LeakyReLU.
// == v5/v7 exactly (best measured: 107-110us, VGPR 112, MfmaUtil 29%).
// wf register double-buffer at DISTANCE 1 only (distance-2 crossed the
// VGPR tier: 112->176, occupancy halved, 2x slower).
// ---------------------------------------------------------------------------
__global__ __launch_bounds__(256) void conv_mfma(
    const __hip_bfloat16* __restrict__ z, const __hip_bfloat16* __restrict__ blob,
    const float* __restrict__ bo, const float* __restrict__ gm,
    const float* __restrict__ bt, const float* __restrict__ mn,
    const float* __restrict__ vr, float* __restrict__ out) {
  __shared__ short zs[2][3 * 66 * 40];
  const int idx0 = blockIdx.x;
  // XCD swizzle: xcd = idx&7 owns h-slice [8*xcd, 8*xcd+8) for all b.
  const int h = (idx0 & 7) * 8 + ((idx0 >> 3) & 7);
  const int b = idx0 >> 6;
  const int tid = threadIdx.x;
  const int wave = tid >> 6, lane = tid & 63;
  const int q = lane >> 4, m = lane & 15;
  float4v acc[4][4] = {};  // [of][wf]

  // Per-thread staging chunks: idx = tid + k*256, k<4 (792 chunks total).
  int s_r[4], s_wp[4], s_cg[4];
  bool s_ok[4], s_act[4];
  const __hip_bfloat16* s_base[4];
#pragma unroll
  for (int k = 0; k < 4; ++k) {
    int idx = tid + k * 256;
    bool act = idx < 792;
    int cg = idx & 3;
    int t2 = idx >> 2;
    int wpos = act ? (t2 % 66) : 0;
    int r = act ? (t2 / 66) : 0;
    int h_in = h - 1 + r;
    int w_in = wpos - 1;
    bool ok = act && h_in >= 0 && h_in < 64 && w_in >= 0 && w_in < 64;
    if (!act) { r = 0; wpos = 0; cg = 0; }
    s_r[k] = r; s_wp[k] = wpos; s_cg[k] = cg;
    s_ok[k] = ok; s_act[k] = act;
    s_base[k] = z + ((size_t)((b * 64 + h_in) * 64 + w_in)) * 256 + cg * 8;
  }

  uint4 pf[4];
  // prefetch z cb=0
#pragma unroll
  for (int k = 0; k < 4; ++k)
    pf[k] = s_ok[k] ? *reinterpret_cast<const uint4*>(s_base[k])
                    : make_uint4(0u, 0u, 0u, 0u);
#pragma unroll
  for (int k = 0; k < 4; ++k)
    if (s_act[k])
      *reinterpret_cast<uint4*>(
          &zs[0][(s_r[k] * 66 + s_wp[k]) * 40 + s_cg[k] * 8]) = pf[k];

  // wf pipeline: preload (cb=0, tap=0)
  short8 wfb[2][4];
#pragma unroll
  for (int of = 0; of < 4; ++of)
    wfb[0][of] = *reinterpret_cast<const short8*>(
        blob + ((size_t)((0 * 16 + wave * 4 + of) * 64 + lane)) * 8);
  __syncthreads();

#pragma unroll 2
  for (int cb = 0; cb < 8; ++cb) {
    const short* cur = zs[cb & 1];
    short* nxt = zs[(cb + 1) & 1];
    // issue next-cb z loads (land during compute)
    if (cb < 7) {
#pragma unroll
      for (int k = 0; k < 4; ++k)
        pf[k] = s_ok[k] ? *reinterpret_cast<const uint4*>(
                              s_base[k] + (size_t)(cb + 1) * 32)
                        : make_uint4(0u, 0u, 0u, 0u);
    }
    // compute on cur; wf double-buffered one tap ahead
#pragma unroll
    for (int tap = 0; tap < 9; ++tap) {
      const int kh = tap / 3, kw = tap % 3;
      const int p = (cb + tap) & 1;        // compile-time (cb unrolled)
      // prefetch next tap's weights (or next cb's tap 0)
      {
        const int ntap = (tap == 8) ? 0 : tap + 1;
        const int ncb = (tap == 8) ? cb + 1 : cb;
        if (ncb < 8) {
#pragma unroll
          for (int of = 0; of < 4; ++of)
            wfb[p ^ 1][of] = *reinterpret_cast<const short8*>(
                blob +
                ((size_t)(((ntap * 8 + ncb) * 16 + wave * 4 + of) * 64 + lane)) *
                    8);
        }
      }
      short8 zf[4];
#pragma unroll
      for (int wfi = 0; wfi < 4; ++wfi) {
        int wpos = wfi * 16 + m + kw;
        zf[wfi] = *reinterpret_cast<const short8*>(
            &cur[(kh * 66 + wpos) * 40 + q * 8]);
      }
#pragma unroll
      for (int of = 0; of < 4; ++of)
#pragma unroll
        for (int wfi = 0; wfi < 4; ++wfi)
          acc[of][wfi] = __builtin_amdgcn_mfma_f32_16x16x32_bf16(
              wfb[p][of], zf[wfi], acc[of][wfi], 0, 0, 0);
    }
    if (cb < 7) {
#pragma unroll
      for (int k = 0; k < 4; ++k)
        if (s_act[k])
          *reinterpret_cast<uint4*>(
              &nxt[(s_r[k] * 66 + s_wp[k]) * 40 + s_cg[k] * 8]) = pf[k];
    }
    __syncthreads();
  }
#pragma unroll
  for (int of = 0; of < 4; ++of) {
    int o_base = wave * 64 + of * 16 + q * 4;
#pragma unroll
    for (int r = 0; r < 4; ++r) {
      int o = o_base + r;
      float sc = gm[o] * rsqrtf(vr[o] + 1e-5f);
      float sh = bt[o] + (bo[o] - mn[o]) * sc;
#pragma unroll
      for (int wfi = 0; wfi < 4; ++wfi) {
        float y = acc[of][wfi][r] * sc + sh;
        y = (y >= 0.f) ? y : 0.2f * y;
        out[(((size_t)(b * 256 + o)) * 64 + h) * 64 + wfi * 16 + m] = y;
      }
    }
  }
}

extern "C" void kernel_launch(void* const* d_in, const int* in_sizes, int n_in,
                              void* d_out, int out_size, void* d_ws,
                              size_t ws_size, hipStream_t stream) {
  (void)in_sizes; (void)n_in; (void)out_size; (void)ws_size;
  const float* x  = (const float*)d_in[0];
  const float* wq = (const float*)d_in[1];
  const float* bq = (const float*)d_in[2];
  const float* wk = (const float*)d_in[3];
  const float* bk = (const float*)d_in[4];
  const float* wv = (const float*)d_in[5];
  const float* bv = (const float*)d_in[6];
  const float* wo = (const float*)d_in[7];
  const float* bo = (const float*)d_in[8];
  const float* gm = (const float*)d_in[9];
  const float* bt = (const float*)d_in[10];
  const float* mn = (const float*)d_in[11];
  const float* vr = (const float*)d_in[12];
  float* out = (float*)d_out;

  char* ws = (char*)d_ws;
  __hip_bfloat16* qb = (__hip_bfloat16*)(ws);             // 32 MB q NCHW; reused: z NHWC
  __hip_bfloat16* kb = (__hip_bfloat16*)(ws + 33554432);  // 32 MB k NCHW
  __hip_bfloat16* attnb = (__hip_bfloat16*)(ws + 67371008);  // 128 KB bf16
  __hip_bfloat16* blob = (__hip_bfloat16*)(ws + 67502080);   // 1.125 MB conv W
  // d_out scratch layout (all dead before conv_mfma overwrites d_out):
  //   [0, 32MB)        v NHWC bf16
  //   [32MB, 32.4MB)   qkv W blob
  //   [36MB, 52MB)     scores partials f32 [64 slices][B][64][64]
  __hip_bfloat16* vb = (__hip_bfloat16*)d_out;
  __hip_bfloat16* blob_a = (__hip_bfloat16*)((char*)d_out + 33554432);
  float* part = (float*)((char*)d_out + 37748736);

  wprep_all<<<384, 256, 0, stream>>>(wo, wq, wk, wv, blob, blob_a);
  qkv_mfma<<<dim3(64, BB, 3), 256, 0, stream>>>(x, blob_a, bq, bk, bv,
                                                qb, kb, vb);
  scores_mfma<<<dim3(64, BB), 256, 0, stream>>>(qb, kb, part);
  softmax_kernel<<<dim3(64, BB), 64, 0, stream>>>(part, attnb);
  apply_mfma<<<dim3(64, BB), 256, 0, stream>>>(attnb, vb, qb /* z NHWC */);
  conv_mfma<<<dim3(BB * 64), 256, 0, stream>>>(qb, blob, bo, gm, bt, mn, vr,
                                               out);
}

// Round 14
// 298.460 us; speedup vs baseline: 1.0510x; 1.0510x over previous
//
#include <hip/hip_runtime.h>
#include <hip/hip_bf16.h>

// B=16, D=256, H=64, W=64, S=4096, P=8, tokens T=64, E=D*64=16384
// Inputs/outputs FLOAT32 (per reference). Intermediates bf16.
#define BB 16
#define SS 4096

typedef __attribute__((ext_vector_type(8))) short short8;
typedef __attribute__((ext_vector_type(4))) float float4v;

// ---------------------------------------------------------------------------
// K0: fused weight prep. blocks [0,288): conv W -> B-frag blob.
// blocks [288,384): Wq/Wk/Wv -> A-frag blob.
// ---------------------------------------------------------------------------
__global__ __launch_bounds__(256) void wprep_all(
    const float* __restrict__ wo, const float* __restrict__ wq,
    const float* __restrict__ wk, const float* __restrict__ wv,
    __hip_bfloat16* __restrict__ blob, __hip_bfloat16* __restrict__ blob_a) {
  const int bid = blockIdx.x;
  const int tid = threadIdx.x;
  if (bid < 288) {
    int chunk = bid * 256 + tid;  // 73728 = 9*8*16*64 exact
    int l = chunk & 63;
    int ob = (chunk >> 6) & 15;
    int cb = (chunk >> 10) & 7;
    int tap = chunk >> 13;
    int o = ob * 16 + (l & 15);
    int c0 = cb * 32 + (l >> 4) * 8;
    union { uint4 u; __hip_bfloat16 h[8]; } t;
#pragma unroll
    for (int j = 0; j < 8; ++j)
      t.h[j] = __float2bfloat16(wo[((size_t)(o * 256 + c0 + j)) * 9 + tap]);
    *reinterpret_cast<uint4*>(blob + (size_t)chunk * 8) = t.u;
  } else {
    int chunk = (bid - 288) * 256 + tid;  // 24576 = 3*8*16*64 exact
    int lane = chunk & 63;
    int ob = (chunk >> 6) & 15;
    int cb = (chunk >> 10) & 7;
    int which = chunk >> 13;
    const float* W = (which == 0) ? wq : (which == 1) ? wk : wv;
    int o = ob * 16 + (lane & 15);
    int c0 = cb * 32 + (lane >> 4) * 8;
    const float* p = W + o * 256 + c0;
    union { uint4 u; __hip_bfloat16 h[8]; } t;
#pragma unroll
    for (int j = 0; j < 8; ++j) t.h[j] = __float2bfloat16(p[j]);
    *reinterpret_cast<uint4*>(blob_a + (size_t)chunk * 8) = t.u;
  }
}

// ---------------------------------------------------------------------------
// K1: MFMA QKV GEMM (3-pass: blockIdx.z = which). v8 main loop (unswapped,
// dbuf LDS, 1 barrier/cb). R10: q/k epilogue LDS transpose (8x128B segments
// per store instr). R12: same mechanism for the v pass (old uint2 NHWC
// stores were 64x8B isolated segments/instr). Both verified.
// ---------------------------------------------------------------------------
__global__ __launch_bounds__(256, 4) void qkv_mfma(
    const float* __restrict__ x, const __hip_bfloat16* __restrict__ blob,
    const float* __restrict__ bq, const float* __restrict__ bk,
    const float* __restrict__ bv,
    __hip_bfloat16* __restrict__ qb, __hip_bfloat16* __restrict__ kb,
    __hip_bfloat16* __restrict__ vb) {
  __shared__ short ls[9216];  // staging: 2 x 2560; epilogue: per-wave regions
  const int which = blockIdx.z;
  const int b = blockIdx.y;
  const int s0 = blockIdx.x * 64;
  const float* bias = (which == 0) ? bq : (which == 1) ? bk : bv;
  __hip_bfloat16* outb = (which == 0) ? qb : kb;  // v handled separately
  const int tid = threadIdx.x;
  const int wave = tid >> 6, lane = tid & 63;
  const int q = lane >> 4, m = lane & 15;
  const int sl = tid & 63;
  const int cg = tid >> 6;
  float4v acc[4][4] = {};  // [of][sf]; row = o-sub (q*4+r), col = s-sub (m)

  const float* xbase = x + ((size_t)(b * 256 + cg * 8)) * SS + s0 + sl;
  float xr[8];
#pragma unroll
  for (int i = 0; i < 8; ++i) xr[i] = xbase[(size_t)i * SS];
  {
    union { uint4 u; __hip_bfloat16 h[8]; } t;
#pragma unroll
    for (int i = 0; i < 8; ++i) t.h[i] = __float2bfloat16(xr[i]);
    *reinterpret_cast<uint4*>(&ls[sl * 40 + cg * 8]) = t.u;
  }
  __syncthreads();

  for (int cb = 0; cb < 8; ++cb) {
    const short* cur = &ls[(cb & 1) * 2560];
    short* nxt = &ls[((cb + 1) & 1) * 2560];
    if (cb < 7) {
#pragma unroll
      for (int i = 0; i < 8; ++i)
        xr[i] = xbase[(size_t)(cb + 1) * 32 * SS + (size_t)i * SS];
    }
    short8 af[4];
#pragma unroll
    for (int of = 0; of < 4; ++of)
      af[of] = *reinterpret_cast<const short8*>(
          blob +
          ((size_t)(((which * 8 + cb) * 16 + wave * 4 + of) * 64 + lane)) * 8);
    short8 xf[4];
#pragma unroll
    for (int sf = 0; sf < 4; ++sf)
      xf[sf] =
          *reinterpret_cast<const short8*>(&cur[(sf * 16 + m) * 40 + q * 8]);
#pragma unroll
    for (int of = 0; of < 4; ++of)
#pragma unroll
      for (int sf = 0; sf < 4; ++sf)
        acc[of][sf] = __builtin_amdgcn_mfma_f32_16x16x32_bf16(
            af[of], xf[sf], acc[of][sf], 0, 0, 0);
    if (cb < 7) {
      union { uint4 u; __hip_bfloat16 h[8]; } t;
#pragma unroll
      for (int i = 0; i < 8; ++i) t.h[i] = __float2bfloat16(xr[i]);
      *reinterpret_cast<uint4*>(&nxt[sl * 40 + cg * 8]) = t.u;
    }
    __syncthreads();
  }
  if (which == 2) {
    // v NHWC via per-wave epilogue LDS transpose. Wave owns o-range
    // [wave*64, wave*64+64) x all 64 w of pixel row h. Two 32-w halves
    // through a private [32 w][72] region (stride 144B keeps b128 align).
    const int h = s0 >> 6;
    __hip_bfloat16* tw = reinterpret_cast<__hip_bfloat16*>(ls) + wave * 2304;
#pragma unroll
    for (int wh = 0; wh < 2; ++wh) {
      // write phase: lane (q,m) drops 32 values (2 sf x 4 of x 4 r)
#pragma unroll
      for (int sf2 = 0; sf2 < 2; ++sf2) {
        int sf = wh * 2 + sf2;
#pragma unroll
        for (int of = 0; of < 4; ++of)
#pragma unroll
          for (int r = 0; r < 4; ++r)
            tw[(sf2 * 16 + m) * 72 + of * 16 + q * 4 + r] = __float2bfloat16(
                acc[of][sf][r] + bias[wave * 64 + of * 16 + q * 4 + r]);
      }
      // read+store: instr i covers 8 w-pixels x 128B contiguous each
#pragma unroll
      for (int i = 0; i < 4; ++i) {
        int w_local = i * 8 + (lane >> 3);
        int oc = lane & 7;
        uint4 vv =
            *reinterpret_cast<const uint4*>(&tw[w_local * 72 + oc * 8]);
        int w = wh * 32 + w_local;
        *reinterpret_cast<uint4*>(vb +
                                  ((size_t)((b * 64 + h) * 64 + w)) * 256 +
                                  wave * 64 + oc * 8) = vv;
      }
    }
  } else {
    // q/k: per-wave LDS transpose (16x72-short private region; 72-stride
    // keeps rows 144B = 16B-aligned for b128 reads). Last __syncthreads()
    // above guarantees all waves are done with the staging buffers.
    __hip_bfloat16* tw =
        reinterpret_cast<__hip_bfloat16*>(ls) + wave * (16 * 72);
#pragma unroll
    for (int of = 0; of < 4; ++of) {
      // write phase: lane (q,m) drops its 16 values at [q*4+r][sf*16+m]
#pragma unroll
      for (int sf = 0; sf < 4; ++sf)
#pragma unroll
        for (int r = 0; r < 4; ++r)
          tw[(q * 4 + r) * 72 + sf * 16 + m] = __float2bfloat16(
              acc[of][sf][r] + bias[wave * 64 + of * 16 + q * 4 + r]);
      // read+store: 8 o-rows x 128B contiguous per instruction
#pragma unroll
      for (int it = 0; it < 2; ++it) {
        int o_local = (lane >> 3) + it * 8;
        int s_oct = lane & 7;
        uint4 vv =
            *reinterpret_cast<const uint4*>(&tw[o_local * 72 + s_oct * 8]);
        int o = wave * 64 + of * 16 + o_local;
        *reinterpret_cast<uint4*>(outb + (size_t)(b * 256 + o) * SS + s0 +
                                  s_oct * 8) = vv;
      }
    }
  }
}

// ---------------------------------------------------------------------------
// K2: MFMA scores. Writes per-d-slice PARTIALS (no atomics, no memset);
// softmax sums the 32 slices. part[slice][b][t][t'] f32.
// 32 slices / grid (32,B) is the measured optimum: 16 was 1 block/CU
// (latency-bound, R5), 64 doubled partials traffic past TLP saturation
// and regressed 14us (R13).
// ---------------------------------------------------------------------------
__global__ __launch_bounds__(256) void scores_mfma(
    const __hip_bfloat16* __restrict__ qb, const __hip_bfloat16* __restrict__ kb,
    float* __restrict__ part) {
  const int b = blockIdx.y;
  const int d0 = blockIdx.x * 8;
  const int tid = threadIdx.x;
  const int wave = tid >> 6, lane = tid & 63;
  const int q = lane >> 4, m = lane & 15;
  const int t = wave * 16 + m;
  const int arow = (t >> 3) * 8;
  const int acol = (t & 7) * 8;
  float4v acc[4] = {};

  for (int dd = 0; dd < 8; ++dd) {
    const int d = d0 + dd;
    const __hip_bfloat16* qp = qb + ((size_t)(b * 256 + d)) * SS;
    const __hip_bfloat16* kp = kb + ((size_t)(b * 256 + d)) * SS;
#pragma unroll
    for (int khalf = 0; khalf < 2; ++khalf) {
      const int oh = khalf * 4 + q;
      short8 af = *reinterpret_cast<const short8*>(
          qp + (arow + oh) * 64 + acol);
      short8 bf[4];
#pragma unroll
      for (int nt = 0; nt < 4; ++nt) {
        int tp = nt * 16 + m;
        bf[nt] = *reinterpret_cast<const short8*>(
            kp + ((tp >> 3) * 8 + oh) * 64 + (tp & 7) * 8);
      }
#pragma unroll
      for (int nt = 0; nt < 4; ++nt)
        acc[nt] = __builtin_amdgcn_mfma_f32_16x16x32_bf16(af, bf[nt], acc[nt],
                                                          0, 0, 0);
    }
  }
  float* pp = part + ((size_t)(blockIdx.x * BB + b)) * 4096;
#pragma unroll
  for (int nt = 0; nt < 4; ++nt)
#pragma unroll
    for (int r = 0; r < 4; ++r)
      pp[(wave * 16 + q * 4 + r) * 64 + nt * 16 + m] = acc[nt][r];
}

// ---------------------------------------------------------------------------
// K3: softmax over t' with scale 1/128; sums 32 d-slice partials first.
// ---------------------------------------------------------------------------
__global__ __launch_bounds__(64) void softmax_kernel(
    const float* __restrict__ part, __hip_bfloat16* __restrict__ attnb) {
  const int t = blockIdx.x;
  const int b = blockIdx.y;
  const int lane = threadIdx.x;
  float v = 0.f;
#pragma unroll
  for (int sl = 0; sl < 32; ++sl)
    v += part[((size_t)(sl * BB + b)) * 4096 + t * 64 + lane];
  v *= 0.0078125f;  // 1/sqrt(16384)
  float m = v;
#pragma unroll
  for (int off = 32; off >= 1; off >>= 1) m = fmaxf(m, __shfl_xor(m, off));
  float e = __expf(v - m);
  float s = e;
#pragma unroll
  for (int off = 32; off >= 1; off >>= 1) s += __shfl_xor(s, off);
  attnb[(b * 64 + t) * 64 + lane] = __float2bfloat16(e / s);
}

// ---------------------------------------------------------------------------
// K4: MFMA apply. z[t][d] = sum_t' attn[t][t'] V[t'][d]; z NHWC bf16.
// R11 form: epilogue LDS transpose for the z store.
// ---------------------------------------------------------------------------
__global__ __launch_bounds__(256) void apply_mfma(
    const __hip_bfloat16* __restrict__ attnb, const __hip_bfloat16* __restrict__ vb,
    __hip_bfloat16* __restrict__ zb) {
  __shared__ short sbuf[4 * 64 * 72];  // 36864B; phase1: Vs[64][268]
  short (*Vs)[268] = reinterpret_cast<short(*)[268]>(sbuf);
  const int off = blockIdx.x;
  const int b = blockIdx.y;
  const int oh = off >> 3, ow = off & 7;
  const int tid = threadIdx.x;
#pragma unroll
  for (int i = 0; i < 8; ++i) {
    int chunk = i * 256 + tid;
    int tp = chunk >> 5;
    int cg = chunk & 31;
    int hh = (tp >> 3) * 8 + oh;
    int wwp = (tp & 7) * 8 + ow;
    uint4 val = *reinterpret_cast<const uint4*>(
        vb + ((size_t)((b * 64 + hh) * 64 + wwp)) * 256 + cg * 8);
    *reinterpret_cast<uint4*>(&Vs[tp][cg * 8]) = val;
  }
  __syncthreads();
  const int wave = tid >> 6, lane = tid & 63;
  const int q = lane >> 4, m = lane & 15;
  float4v acc[4][4] = {};
#pragma unroll
  for (int ks = 0; ks < 2; ++ks) {
    short8 af[4];
#pragma unroll
    for (int mt = 0; mt < 4; ++mt)
      af[mt] = *reinterpret_cast<const short8*>(
          attnb + (b * 64 + mt * 16 + m) * 64 + ks * 32 + q * 8);
    short8 bf[4];
#pragma unroll
    for (int nt = 0; nt < 4; ++nt) {
      int d = wave * 64 + nt * 16 + m;
      union { short8 v; short s[8]; } t;
#pragma unroll
      for (int j = 0; j < 8; ++j) t.s[j] = Vs[ks * 32 + q * 8 + j][d];
      bf[nt] = t.v;
    }
#pragma unroll
    for (int mt = 0; mt < 4; ++mt)
#pragma unroll
      for (int nt = 0; nt < 4; ++nt)
        acc[mt][nt] = __builtin_amdgcn_mfma_f32_16x16x32_bf16(
            af[mt], bf[nt], acc[mt][nt], 0, 0, 0);
  }
  // --- epilogue transpose: all waves must be done reading Vs ---
  __syncthreads();
  short* tw = &sbuf[wave * 64 * 72];
#pragma unroll
  for (int mt = 0; mt < 4; ++mt)
#pragma unroll
    for (int r = 0; r < 4; ++r) {
      int t = mt * 16 + q * 4 + r;
#pragma unroll
      for (int nt = 0; nt < 4; ++nt) {
        __hip_bfloat16 hv = __float2bfloat16(acc[mt][nt][r]);
        tw[t * 72 + nt * 16 + m] = *reinterpret_cast<short*>(&hv);
      }
    }
#pragma unroll
  for (int i = 0; i < 8; ++i) {
    int t = i * 8 + (lane >> 3);
    int dg = lane & 7;
    uint4 vv = *reinterpret_cast<const uint4*>(&tw[t * 72 + dg * 8]);
    int h = (t >> 3) * 8 + oh;
    int w = (t & 7) * 8 + ow;
    *reinterpret_cast<uint4*>(
        zb + ((size_t)((b * 64 + h) * 64 + w)) * 256 + wave * 64 + dg * 8) =
        vv;
  }
}

// ---------------------------------------------------------------------------
// K5: MFMA implicit-GEMM 3x3 conv + bias + BN + LeakyReLU.
// == v5/v7 exactly (best measured: 107-110us, VGPR 112, MfmaUtil 29%).
// wf register double-buffer at DISTANCE 1 only (distance-2 crossed the
// VGPR tier: 112->176, occupancy halved, 2x slower).
// ---------------------------------------------------------------------------
__global__ __launch_bounds__(256) void conv_mfma(
    const __hip_bfloat16* __restrict__ z, const __hip_bfloat16* __restrict__ blob,
    const float* __restrict__ bo, const float* __restrict__ gm,
    const float* __restrict__ bt, const float* __restrict__ mn,
    const float* __restrict__ vr, float* __restrict__ out) {
  __shared__ short zs[2][3 * 66 * 40];
  const int idx0 = blockIdx.x;
  // XCD swizzle: xcd = idx&7 owns h-slice [8*xcd, 8*xcd+8) for all b.
  const int h = (idx0 & 7) * 8 + ((idx0 >> 3) & 7);
  const int b = idx0 >> 6;
  const int tid = threadIdx.x;
  const int wave = tid >> 6, lane = tid & 63;
  const int q = lane >> 4, m = lane & 15;
  float4v acc[4][4] = {};  // [of][wf]

  // Per-thread staging chunks: idx = tid + k*256, k<4 (792 chunks total).
  int s_r[4], s_wp[4], s_cg[4];
  bool s_ok[4], s_act[4];
  const __hip_bfloat16* s_base[4];
#pragma unroll
  for (int k = 0; k < 4; ++k) {
    int idx = tid + k * 256;
    bool act = idx < 792;
    int cg = idx & 3;
    int t2 = idx >> 2;
    int wpos = act ? (t2 % 66) : 0;
    int r = act ? (t2 / 66) : 0;
    int h_in = h - 1 + r;
    int w_in = wpos - 1;
    bool ok = act && h_in >= 0 && h_in < 64 && w_in >= 0 && w_in < 64;
    if (!act) { r = 0; wpos = 0; cg = 0; }
    s_r[k] = r; s_wp[k] = wpos; s_cg[k] = cg;
    s_ok[k] = ok; s_act[k] = act;
    s_base[k] = z + ((size_t)((b * 64 + h_in) * 64 + w_in)) * 256 + cg * 8;
  }

  uint4 pf[4];
  // prefetch z cb=0
#pragma unroll
  for (int k = 0; k < 4; ++k)
    pf[k] = s_ok[k] ? *reinterpret_cast<const uint4*>(s_base[k])
                    : make_uint4(0u, 0u, 0u, 0u);
#pragma unroll
  for (int k = 0; k < 4; ++k)
    if (s_act[k])
      *reinterpret_cast<uint4*>(
          &zs[0][(s_r[k] * 66 + s_wp[k]) * 40 + s_cg[k] * 8]) = pf[k];

  // wf pipeline: preload (cb=0, tap=0)
  short8 wfb[2][4];
#pragma unroll
  for (int of = 0; of < 4; ++of)
    wfb[0][of] = *reinterpret_cast<const short8*>(
        blob + ((size_t)((0 * 16 + wave * 4 + of) * 64 + lane)) * 8);
  __syncthreads();

#pragma unroll 2
  for (int cb = 0; cb < 8; ++cb) {
    const short* cur = zs[cb & 1];
    short* nxt = zs[(cb + 1) & 1];
    // issue next-cb z loads (land during compute)
    if (cb < 7) {
#pragma unroll
      for (int k = 0; k < 4; ++k)
        pf[k] = s_ok[k] ? *reinterpret_cast<const uint4*>(
                              s_base[k] + (size_t)(cb + 1) * 32)
                        : make_uint4(0u, 0u, 0u, 0u);
    }
    // compute on cur; wf double-buffered one tap ahead
#pragma unroll
    for (int tap = 0; tap < 9; ++tap) {
      const int kh = tap / 3, kw = tap % 3;
      const int p = (cb + tap) & 1;        // compile-time (cb unrolled)
      // prefetch next tap's weights (or next cb's tap 0)
      {
        const int ntap = (tap == 8) ? 0 : tap + 1;
        const int ncb = (tap == 8) ? cb + 1 : cb;
        if (ncb < 8) {
#pragma unroll
          for (int of = 0; of < 4; ++of)
            wfb[p ^ 1][of] = *reinterpret_cast<const short8*>(
                blob +
                ((size_t)(((ntap * 8 + ncb) * 16 + wave * 4 + of) * 64 + lane)) *
                    8);
        }
      }
      short8 zf[4];
#pragma unroll
      for (int wfi = 0; wfi < 4; ++wfi) {
        int wpos = wfi * 16 + m + kw;
        zf[wfi] = *reinterpret_cast<const short8*>(
            &cur[(kh * 66 + wpos) * 40 + q * 8]);
      }
#pragma unroll
      for (int of = 0; of < 4; ++of)
#pragma unroll
        for (int wfi = 0; wfi < 4; ++wfi)
          acc[of][wfi] = __builtin_amdgcn_mfma_f32_16x16x32_bf16(
              wfb[p][of], zf[wfi], acc[of][wfi], 0, 0, 0);
    }
    if (cb < 7) {
#pragma unroll
      for (int k = 0; k < 4; ++k)
        if (s_act[k])
          *reinterpret_cast<uint4*>(
              &nxt[(s_r[k] * 66 + s_wp[k]) * 40 + s_cg[k] * 8]) = pf[k];
    }
    __syncthreads();
  }
#pragma unroll
  for (int of = 0; of < 4; ++of) {
    int o_base = wave * 64 + of * 16 + q * 4;
#pragma unroll
    for (int r = 0; r < 4; ++r) {
      int o = o_base + r;
      float sc = gm[o] * rsqrtf(vr[o] + 1e-5f);
      float sh = bt[o] + (bo[o] - mn[o]) * sc;
#pragma unroll
      for (int wfi = 0; wfi < 4; ++wfi) {
        float y = acc[of][wfi][r] * sc + sh;
        y = (y >= 0.f) ? y : 0.2f * y;
        out[(((size_t)(b * 256 + o)) * 64 + h) * 64 + wfi * 16 + m] = y;
      }
    }
  }
}

extern "C" void kernel_launch(void* const* d_in, const int* in_sizes, int n_in,
                              void* d_out, int out_size, void* d_ws,
                              size_t ws_size, hipStream_t stream) {
  (void)in_sizes; (void)n_in; (void)out_size; (void)ws_size;
  const float* x  = (const float*)d_in[0];
  const float* wq = (const float*)d_in[1];
  const float* bq = (const float*)d_in[2];
  const float* wk = (const float*)d_in[3];
  const float* bk = (const float*)d_in[4];
  const float* wv = (const float*)d_in[5];
  const float* bv = (const float*)d_in[6];
  const float* wo = (const float*)d_in[7];
  const float* bo = (const float*)d_in[8];
  const float* gm = (const float*)d_in[9];
  const float* bt = (const float*)d_in[10];
  const float* mn = (const float*)d_in[11];
  const float* vr = (const float*)d_in[12];
  float* out = (float*)d_out;

  char* ws = (char*)d_ws;
  __hip_bfloat16* qb = (__hip_bfloat16*)(ws);             // 32 MB q NCHW; reused: z NHWC
  __hip_bfloat16* kb = (__hip_bfloat16*)(ws + 33554432);  // 32 MB k NCHW
  __hip_bfloat16* attnb = (__hip_bfloat16*)(ws + 67371008);  // 128 KB bf16
  __hip_bfloat16* blob = (__hip_bfloat16*)(ws + 67502080);   // 1.125 MB conv W
  // d_out scratch layout (all dead before conv_mfma overwrites d_out):
  //   [0, 32MB)        v NHWC bf16
  //   [32MB, 32.4MB)   qkv W blob
  //   [36MB, 44MB)     scores partials f32 [32 slices][B][64][64]
  __hip_bfloat16* vb = (__hip_bfloat16*)d_out;
  __hip_bfloat16* blob_a = (__hip_bfloat16*)((char*)d_out + 33554432);
  float* part = (float*)((char*)d_out + 37748736);

  wprep_all<<<384, 256, 0, stream>>>(wo, wq, wk, wv, blob, blob_a);
  qkv_mfma<<<dim3(64, BB, 3), 256, 0, stream>>>(x, blob_a, bq, bk, bv,
                                                qb, kb, vb);
  scores_mfma<<<dim3(32, BB), 256, 0, stream>>>(qb, kb, part);
  softmax_kernel<<<dim3(64, BB), 64, 0, stream>>>(part, attnb);
  apply_mfma<<<dim3(64, BB), 256, 0, stream>>>(attnb, vb, qb /* z NHWC */);
  conv_mfma<<<dim3(BB * 64), 256, 0, stream>>>(qb, blob, bo, gm, bt, mn, vr,
                                               out);
}